// Round 1
// baseline (334.131 us; speedup 1.0000x reference)
//
#include <hip/hip_runtime.h>

// LNCC with separable 5-tap Gaussian blur (sigma=1), fully fused single pass.
// Shapes: (N=2, C=1, D=160, H=192, W=224) fp32. Output: scalar fp32.

#define NB 2
#define DD 160
#define HH 192
#define WW 224
#define SH 224                 // H stride
#define SD (224*192)           // D stride = 43008
#define SN (224*192*160)       // N stride = 6881280

#define TW 32                  // output tile width
#define TH 8                   // output tile height
#define DCHUNK 40              // D-slices per block
#define NCHUNK (DD/DCHUNK)     // 4

__device__ __constant__ float KW[5] = {
    0.05448868f, 0.24420134f, 0.40261995f, 0.24420134f, 0.05448868f
};

__global__ __launch_bounds__(256) void lncc_main(
    const float* __restrict__ A, const float* __restrict__ B,
    const float* __restrict__ M, double* __restrict__ acc)
{
    // tiles: raw input (TH+4)x(TW+4) = 12x36 ; W-blur (TH+4)xTW = 12x32 ; ring 5 slots of THxTW
    __shared__ float sI[12][36];
    __shared__ float sJ[12][36];
    __shared__ float wb[5][12][32];      // [ch][r][c]
    __shared__ float ring[5][5][TH][TW]; // [ch][slot][r][c]
    __shared__ float redL[4], redM[4];

    const int wt = blockIdx.x;           // 0..6
    const int ht = blockIdx.y;           // 0..23
    const int zz = blockIdx.z;           // 0..7
    const int n  = zz >> 2;
    const int dc = zz & 3;
    const int w0 = wt * TW, h0 = ht * TH, d0 = dc * DCHUNK;

    const float* Ai = A + (size_t)n * SN;
    const float* Bi = B + (size_t)n * SN;
    const float* Mi = M + (size_t)n * SN;

    const int tid = threadIdx.x;
    const int r_out = tid >> 5;          // 0..7
    const int c_out = tid & 31;          // 0..31

    float accL = 0.f, accM = 0.f;

    for (int dd = d0 - 2; dd <= d0 + DCHUNK + 1; ++dd) {
        const bool dvalid = (dd >= 0) && (dd < DD);
        // ---- stage 1: load raw slice (12x36), zero-padded ----
        for (int idx = tid; idx < 12 * 36; idx += 256) {
            const int r = idx / 36, c = idx - r * 36;
            const int gh = h0 + r - 2, gw = w0 + c - 2;
            float vi = 0.f, vj = 0.f;
            if (dvalid && gh >= 0 && gh < HH && gw >= 0 && gw < WW) {
                const size_t off = (size_t)dd * SD + (size_t)gh * SH + gw;
                vi = Ai[off];
                vj = Bi[off];
            }
            sI[r][c] = vi;
            sJ[r][c] = vj;
        }
        __syncthreads();
        // ---- stage 2: W blur -> 5 channels at (12x32) ----
        for (int idx = tid; idx < 12 * 32; idx += 256) {
            const int r = idx >> 5, c = idx & 31;
            float bi = 0.f, bj = 0.f, bij = 0.f, bii = 0.f, bjj = 0.f;
#pragma unroll
            for (int t = 0; t < 5; ++t) {
                const float i = sI[r][c + t];
                const float j = sJ[r][c + t];
                const float k = KW[t];
                bi  += k * i;
                bj  += k * j;
                bij += k * i * j;
                bii += k * i * i;
                bjj += k * j * j;
            }
            wb[0][r][c] = bi;
            wb[1][r][c] = bj;
            wb[2][r][c] = bij;
            wb[3][r][c] = bii;
            wb[4][r][c] = bjj;
        }
        __syncthreads();
        // ---- stage 3: H blur -> ring[., slot] (8x32); one thread per pixel ----
        {
            const int slot = ((dd % 5) + 5) % 5;
#pragma unroll
            for (int ch = 0; ch < 5; ++ch) {
                float s = 0.f;
#pragma unroll
                for (int t = 0; t < 5; ++t) s += KW[t] * wb[ch][r_out + t][c_out];
                ring[ch][slot][r_out][c_out] = s;
            }
            // ---- stage 4: D blur + LNCC for d = dd-2 (same-thread ring, no barrier) ----
            const int d = dd - 2;
            if (d >= d0 && d < d0 + DCHUNK) {
                float bI = 0.f, bJ = 0.f, bIJ = 0.f, bII = 0.f, bJJ = 0.f;
#pragma unroll
                for (int t = 0; t < 5; ++t) {
                    const int sl = (((d - 2 + t) % 5) + 5) % 5;
                    const float k = KW[t];
                    bI  += k * ring[0][sl][r_out][c_out];
                    bJ  += k * ring[1][sl][r_out][c_out];
                    bIJ += k * ring[2][sl][r_out][c_out];
                    bII += k * ring[3][sl][r_out][c_out];
                    bJJ += k * ring[4][sl][r_out][c_out];
                }
                const float cross = bIJ - bI * bJ;
                const float vI = fmaxf(bII - bI * bI, 0.f) + 1e-5f;
                const float vJ = fmaxf(bJJ - bJ * bJ, 0.f) + 1e-5f;
                const float lncc = 1.0f - cross * rsqrtf(vI * vJ);
                const float m = Mi[(size_t)d * SD + (size_t)(h0 + r_out) * SH + (w0 + c_out)];
                accL += lncc * m;
                accM += m;
            }
        }
    }

    // ---- block reduction: wave shuffle (64) then cross-wave LDS ----
#pragma unroll
    for (int off = 32; off > 0; off >>= 1) {
        accL += __shfl_down(accL, off, 64);
        accM += __shfl_down(accM, off, 64);
    }
    const int wave = tid >> 6;
    if ((tid & 63) == 0) { redL[wave] = accL; redM[wave] = accM; }
    __syncthreads();
    if (tid == 0) {
        float sL = redL[0] + redL[1] + redL[2] + redL[3];
        float sM = redM[0] + redM[1] + redM[2] + redM[3];
        atomicAdd(&acc[0], (double)sL);
        atomicAdd(&acc[1], (double)sM);
    }
}

__global__ void lncc_final(const double* __restrict__ acc, float* __restrict__ out)
{
    out[0] = (float)(acc[0] / (acc[1] + 1e-8));
}

extern "C" void kernel_launch(void* const* d_in, const int* in_sizes, int n_in,
                              void* d_out, int out_size, void* d_ws, size_t ws_size,
                              hipStream_t stream)
{
    const float* A = (const float*)d_in[0];
    const float* B = (const float*)d_in[1];
    const float* M = (const float*)d_in[2];
    double* acc = (double*)d_ws;

    hipMemsetAsync(d_ws, 0, 2 * sizeof(double), stream);

    dim3 grid(WW / TW, HH / TH, NB * NCHUNK);   // (7, 24, 8)
    dim3 block(256);
    hipLaunchKernelGGL(lncc_main, grid, block, 0, stream, A, B, M, acc);
    hipLaunchKernelGGL(lncc_final, dim3(1), dim3(1), 0, stream, acc, (float*)d_out);
}